// Round 14
// baseline (149.846 us; speedup 1.0000x reference)
//
#include <hip/hip_runtime.h>
#include <hip/hip_fp16.h>

#define OUT_H 512
#define OUT_W 512
#define BATCH 64
#define CHANS 3

#define WROWS 48
#define WPX   48
// Row-interleaved f16 planes in ONE array: source row r -> A{c0,c1} at
// slot 98r+lx, B{c2,0} at 98r+49+lx. All 8 corner dwords of a pixel sit at
// ONE vaddr + {0,1,49,50,98,99,147,148} -> 4x ds_read2_b32.
#define RSTRIDE 98
#define LSZ 4704                 // 18816 B
#define IDXMAX (LSZ - 149)

struct Win {
    float xb0, yb0;
    int bx, by;
    bool interior;
};

__device__ __forceinline__ Win make_win(float xb0, float yb0, float c, float s) {
    float xmin = xb0 + fminf(0.0f, 31.0f * c) + fminf(0.0f, -31.0f * s);
    float ymin = yb0 + fminf(0.0f, 31.0f * s) + fminf(0.0f,  31.0f * c);
    float xmax = xb0 + fmaxf(0.0f, 31.0f * c) + fmaxf(0.0f, -31.0f * s);
    float ymax = yb0 + fmaxf(0.0f, 31.0f * s) + fmaxf(0.0f,  31.0f * c);
    Win w;
    int bx0 = min(max((int)floorf(xmin), 0), OUT_W - 1);
    int by0 = min(max((int)floorf(ymin), 0), OUT_H - 1);
    w.bx = min(bx0, OUT_W - WPX);
    w.by = min(by0, OUT_H - WROWS);
    w.interior = (xmin >= 0.0f) & (xmax < 510.0f) &
                 (ymin >= 0.0f) & (ymax < 510.0f);
    w.xb0 = xb0; w.yb0 = yb0;
    return w;
}

// 9 overlapping dwordx4 per thread (16B load shifted 4B back so {c0,c1,c2} =
// .y.z.w). OOB-low only possible for the b==0 origin window.
__device__ __forceinline__ void stage_load(const float* __restrict__ Ub,
                                           const Win& w, int tid, bool origin,
                                           float4 va[9]) {
    const float* gb = Ub + ((size_t)w.by * OUT_W + w.bx) * CHANS;
    if (!origin) {
#pragma unroll
        for (int k = 0; k < 9; ++k) {
            unsigned q = (unsigned)tid + 256u * k;
            unsigned r  = q / 48u;
            unsigned lx = q - r * 48u;
            va[k] = *(const float4*)(gb + (size_t)r * (OUT_W * CHANS) + lx * 3u - 1);
        }
    } else {
#pragma unroll
        for (int k = 0; k < 9; ++k) {
            unsigned q = (unsigned)tid + 256u * k;
            unsigned r  = q / 48u;
            unsigned lx = q - r * 48u;
            const float* p = gb + (size_t)r * (OUT_W * CHANS) + lx * 3u;
            float2 ab = *(const float2*)p;
            float  cc = p[2];
            va[k] = make_float4(0.0f, ab.x, ab.y, cc);
        }
    }
}

__device__ __forceinline__ void stage_write(unsigned int* smf, int tid,
                                            const float4 va[9]) {
#pragma unroll
    for (int k = 0; k < 9; ++k) {
        unsigned q = (unsigned)tid + 256u * k;
        unsigned r  = q / 48u;
        unsigned lx = q - r * 48u;
        unsigned slot = RSTRIDE * r + lx;           // lane-stride 1, conflict-free
        float4 v = va[k];
        __half2 hA = __floats2half2_rn(v.y, v.z);   // {c0,c1}
        __half2 hB = __floats2half2_rn(v.w, 0.0f);  // {c2,0}
        smf[slot]      = *(const unsigned int*)&hA; // ds_write2_b32 {0,49}
        smf[slot + 49] = *(const unsigned int*)&hB;
    }
}

__device__ __forceinline__ void compute_store(const unsigned int* smf,
                                              const Win& w, float c, float s,
                                              int tid, float* __restrict__ po) {
    int il = tid >> 3;                  // 0..31
    int jb = (tid & 7) << 2;            // 0,4,...,28
    float xr = w.xb0 + c * (float)jb - s * (float)il;
    float yr = w.yb0 + s * (float)jb + c * (float)il;
    int Koff = w.by * RSTRIDE + w.bx;
    bool interior = w.interior;

    float o[12];
#pragma unroll
    for (int p = 0; p < 4; ++p) {
        float x = fmaf(c, (float)p, xr);
        float y = fmaf(s, (float)p, yr);
        int ix = __float2int_rd(x);
        int iy = __float2int_rd(y);
        float fx = x - (float)ix;
        float fy = y - (float)iy;

        int idx = iy * RSTRIDE + ix - Koff;
        if (!interior) idx = min(max(idx, 0), IDXMAX);  // v_med3; masked safe

        const unsigned int* lp = smf + idx;             // ONE vaddr, 4x ds_read2
        unsigned iA0 = lp[0],   iA1 = lp[1];
        unsigned iB0 = lp[49],  iB1 = lp[50];
        unsigned iA2 = lp[98],  iA3 = lp[99];
        unsigned iB2 = lp[147], iB3 = lp[148];

        __half2 fx2 = __float2half2_rn(fx);
        __half2 fy2 = __float2half2_rn(fy);
        __half2 a01 = *(const __half2*)&iA0, c01 = *(const __half2*)&iA1;
        __half2 a2  = *(const __half2*)&iB0, c2  = *(const __half2*)&iB1;
        __half2 b01 = *(const __half2*)&iA2, d01 = *(const __half2*)&iA3;
        __half2 b2  = *(const __half2*)&iB2, d2  = *(const __half2*)&iB3;

        __half2 t01 = __hfma2(fx2, __hsub2(c01, a01), a01);
        __half2 t2  = __hfma2(fx2, __hsub2(c2,  a2),  a2);
        __half2 u01 = __hfma2(fx2, __hsub2(d01, b01), b01);
        __half2 u2  = __hfma2(fx2, __hsub2(d2,  b2),  b2);
        __half2 r01 = __hfma2(fy2, __hsub2(u01, t01), t01);
        __half2 r2  = __hfma2(fy2, __hsub2(u2,  t2),  t2);

        float v0 = __low2float(r01);
        float v1 = __high2float(r01);
        float v2 = __low2float(r2);
        if (!interior) {
            // Reference yields exactly 0 where clamped corners collapse.
            bool valid = ((unsigned)ix < 511u) & ((unsigned)iy < 511u);
            v0 = valid ? v0 : 0.0f;
            v1 = valid ? v1 : 0.0f;
            v2 = valid ? v2 : 0.0f;
        }
        o[p * 3 + 0] = v0;
        o[p * 3 + 1] = v1;
        o[p * 3 + 2] = v2;
    }

    float* pr = po + (size_t)il * (OUT_W * CHANS) + jb * CHANS;
    ((float4*)pr)[0] = make_float4(o[0], o[1], o[2],  o[3]);
    ((float4*)pr)[1] = make_float4(o[4], o[5], o[6],  o[7]);
    ((float4*)pr)[2] = make_float4(o[8], o[9], o[10], o[11]);
}

__global__ __launch_bounds__(256) void st_bilinear_kernel(
    const float* __restrict__ U,      // [B, H, W, C] f32
    const float* __restrict__ theta,  // [B, 1]
    float* __restrict__ out)          // [B, H, W, C] f32
{
    __shared__ __align__(16) unsigned int smf[LSZ];

    // 2048 persistent-ish blocks; each owns 8 horizontally-adjacent 32x32
    // tiles of ONE image. XCD remap: XCD k gets images [k*8, k*8+8).
    int blk  = blockIdx.x;
    int lblk = (blk & 7) * 256 + (blk >> 3);    // 0..2047, bijective
    int base = lblk << 3;                       // first tile id (8 per block)
    int b    = base >> 8;                       // image (uniform; 8 | 256)
    int rem  = base & 255;
    int i0   = (rem >> 4) << 5;                 // tile row (fixed across t)
    int j0b  = (rem & 15) << 5;                 // first tile col
    int tid  = threadIdx.x;

    float tt = theta[__builtin_amdgcn_readfirstlane(b)];
    float s, c;
    __sincosf(tt, &s, &c);

    // x = xb + c*jl - s*il ; y = yb + s*jl + c*il  ((2/511)*255.5 == 1, so
    // stepping 32 output cols shifts source by exactly (32c, 32s)).
    const float scale = 2.0f / 511.0f;
    float gx0 = (float)j0b * scale - 1.0f;
    float gy0 = (float)i0  * scale - 1.0f;
    float xb = (c * gx0 - s * gy0 + 1.0f) * 255.5f;
    float yb = (s * gx0 + c * gy0 + 1.0f) * 255.5f;

    const float* Ub = U + (size_t)b * (OUT_H * OUT_W * CHANS);
    bool b0 = (b == 0);
    float* rowbase = out + (((size_t)b * OUT_H + i0) * OUT_W + j0b) * CHANS;

    Win w = make_win(xb, yb, c, s);
    float4 va[9];
    stage_load(Ub, w, tid, b0 & (w.bx == 0) & (w.by == 0), va);

    // Pipeline: [loads for t in flight] -> stage_write(t) -> issue loads t+1
    // -> barrier -> compute(t) -> barrier. Loads for t+1 hide under compute(t);
    // their vmcnt wait lands at the next stage_write.
#pragma unroll 1
    for (int t = 0; t < 8; ++t) {
        stage_write(smf, tid, va);              // waits on tile t's loads
        Win wn = w;
        if (t < 7) {
            float xbn = xb + 32.0f * c * (float)(t + 1);
            float ybn = yb + 32.0f * s * (float)(t + 1);
            wn = make_win(xbn, ybn, c, s);
            stage_load(Ub, wn, tid, b0 & (wn.bx == 0) & (wn.by == 0), va);
        }
        __syncthreads();                        // LDS tile t ready
        compute_store(smf, w, c, s, tid, rowbase + (size_t)(t << 5) * CHANS);
        if (t < 7) __syncthreads();             // all waves done reading t
        w = wn;
    }
}

extern "C" void kernel_launch(void* const* d_in, const int* in_sizes, int n_in,
                              void* d_out, int out_size, void* d_ws, size_t ws_size,
                              hipStream_t stream) {
    const float* U     = (const float*)d_in[0];
    const float* theta = (const float*)d_in[1];
    float* out = (float*)d_out;

    int blocks = 2048;                  // 16384 tiles / 8 tiles per block
    st_bilinear_kernel<<<blocks, 256, 0, stream>>>(U, theta, out);
}

// Round 15
// 99.967 us; speedup vs baseline: 1.4990x; 1.4990x over previous
//
#include <hip/hip_runtime.h>
#include <hip/hip_fp16.h>

#define OUT_H 512
#define OUT_W 512
#define BATCH 64
#define CHANS 3

#define WROWS 48
#define WPX   48
#define PITCH 49                 // dword slots per LDS row; odd -> gcd(49,32)=1, all banks
#define PLANE (WROWS * PITCH)    // 2352 dwords = 9408 B per plane
#define IDXMAX (PLANE - PITCH - 2)   // 2301: max read = 2301+49+1 = 2351 < 2352

__global__ __launch_bounds__(256) void st_bilinear_kernel(
    const float* __restrict__ U,      // [B, H, W, C] f32
    const float* __restrict__ theta,  // [B, 1]
    float* __restrict__ out)          // [B, H, W, C] f32
{
    // SoA f16 planes, 4B granular: smA[px] = half2{c0,c1}, smB[px] = half2{c2,0}.
    // Odd pitch 49 -> source-row stride hits all 32 banks in every rotation
    // regime; 4B slots -> wave64 min 2 lanes/bank (free).
    __shared__ __align__(16) unsigned int smA[PLANE];
    __shared__ __align__(16) unsigned int smB[PLANE];

    // XCD-aware remap: give XCD k images [k*8, k*8+8) so each 3.1 MB image
    // stays resident in one XCD's 4 MB L2.
    int blk  = blockIdx.x;
    int lblk = (blk & 7) * 2048 + (blk >> 3);

    int b  = lblk >> 8;                 // image (uniform per block)
    int t  = lblk & 255;                // 16x16 tiles of 32x32 px
    int i0 = (t >> 4) << 5;
    int j0 = (t & 15) << 5;

    int tid = threadIdx.x;

    float tt = theta[__builtin_amdgcn_readfirstlane(b)];
    float s, c;
    __sincosf(tt, &s, &c);

    // x = xb0 + c*jl - s*il ; y = yb0 + s*jl + c*il  ((2/511)*255.5 == 1)
    const float scale = 2.0f / 511.0f;
    float gx0 = (float)j0 * scale - 1.0f;
    float gy0 = (float)i0 * scale - 1.0f;
    float xb0 = (c * gx0 - s * gy0 + 1.0f) * 255.5f;
    float yb0 = (s * gx0 + c * gy0 + 1.0f) * 255.5f;

    // Source bbox of the 32x32 tile: span 31(|c|+|s|)+2 <= 46 -> 48 window.
    float xmin = xb0 + fminf(0.0f, 31.0f * c) + fminf(0.0f, -31.0f * s);
    float ymin = yb0 + fminf(0.0f, 31.0f * s) + fminf(0.0f,  31.0f * c);

    int bx0 = min(max((int)floorf(xmin), 0), OUT_W - 1);
    int by0 = min(max((int)floorf(ymin), 0), OUT_H - 1);
    int bx_load = min(bx0, OUT_W - WPX);    // 48x48 window always in-image
    int by_load = min(by0, OUT_H - WROWS);

    const float* Ub = U + (size_t)b * (OUT_H * OUT_W * CHANS);
    const float* gb = Ub + ((size_t)by_load * OUT_W + bx_load) * CHANS;

    // ---- staging: 2304 px, 9 px/thread, lane-linear (12B stride, coalesced),
    // loads hoisted; writes are stride-1 ds_write_b32 (zero bank conflict). ----
    float2 lc01[9];
    float  lc2[9];
#pragma unroll
    for (int k = 0; k < 9; ++k) {
        unsigned q = (unsigned)tid + 256u * k;      // 0..2303
        unsigned r  = q / 48u;                      // magic-mul
        unsigned lx = q - r * 48u;
        const float* p = gb + (size_t)r * (OUT_W * CHANS) + lx * 3u;
        lc01[k] = *(const float2*)p;
        lc2[k]  = p[2];
    }
#pragma unroll
    for (int k = 0; k < 9; ++k) {
        unsigned q = (unsigned)tid + 256u * k;
        unsigned r  = q / 48u;
        unsigned lx = q - r * 48u;
        unsigned slot = r * PITCH + lx;             // lane-stride ~1
        __half2 h01 = __floats2half2_rn(lc01[k].x, lc01[k].y);
        __half2 h2  = __floats2half2_rn(lc2[k], 0.0f);
        smA[slot] = *(const unsigned int*)&h01;
        smB[slot] = *(const unsigned int*)&h2;
    }
    __syncthreads();

    // ---- compute: thread -> 4 consecutive px in one output row ----
    int il = tid >> 3;                  // 0..31
    int jb = (tid & 7) << 2;            // 0,4,...,28
    float xr = xb0 + c * (float)jb - s * (float)il;
    float yr = yb0 + s * (float)jb + c * (float)il;
    int Koff = by_load * PITCH + bx_load;

    float o[12];
#pragma unroll
    for (int p = 0; p < 4; ++p) {
        float x = fmaf(c, (float)p, xr);
        float y = fmaf(s, (float)p, yr);

        int ix = __float2int_rd(x);
        int iy = __float2int_rd(y);
        float fx = x - (float)ix;
        float fy = y - (float)iy;

        int idx = iy * PITCH + ix - Koff;       // (iy-by)*49 + (ix-bx)
        idx = min(max(idx, 0), IDXMAX);         // v_med3; masked px read junk safely

        // 4 x ds_read2_b32: A{0,1}, A{49,50}, B{0,1}, B{49,50}
        unsigned iA0 = smA[idx],         iA1 = smA[idx + 1];
        unsigned iA2 = smA[idx + PITCH], iA3 = smA[idx + PITCH + 1];
        unsigned iB0 = smB[idx],         iB1 = smB[idx + 1];
        unsigned iB2 = smB[idx + PITCH], iB3 = smB[idx + PITCH + 1];

        __half2 fx2 = __float2half2_rn(fx);
        __half2 fy2 = __float2half2_rn(fy);
        __half2 a01 = *(const __half2*)&iA0, c01 = *(const __half2*)&iA1;
        __half2 b01 = *(const __half2*)&iA2, d01 = *(const __half2*)&iA3;
        __half2 a2  = *(const __half2*)&iB0, c2  = *(const __half2*)&iB1;
        __half2 b2  = *(const __half2*)&iB2, d2  = *(const __half2*)&iB3;

        __half2 t01 = __hfma2(fx2, __hsub2(c01, a01), a01);   // top lerp
        __half2 t2  = __hfma2(fx2, __hsub2(c2,  a2),  a2);
        __half2 u01 = __hfma2(fx2, __hsub2(d01, b01), b01);   // bottom lerp
        __half2 u2  = __hfma2(fx2, __hsub2(d2,  b2),  b2);
        __half2 r01 = __hfma2(fy2, __hsub2(u01, t01), t01);   // vertical
        __half2 r2  = __hfma2(fy2, __hsub2(u2,  t2),  t2);

        // Reference yields exactly 0 where clamped corners collapse
        // (x<0, x>=511, y<0, y>=511).
        bool valid = (x >= 0.0f) && (x < 511.0f) && (y >= 0.0f) && (y < 511.0f);
        o[p * 3 + 0] = valid ? __low2float(r01)  : 0.0f;
        o[p * 3 + 1] = valid ? __high2float(r01) : 0.0f;
        o[p * 3 + 2] = valid ? __low2float(r2)   : 0.0f;
    }

    // 4 px = 48 B contiguous, 16B-aligned.
    float* po = out + (((size_t)b * OUT_H + (i0 + il)) * OUT_W + (j0 + jb)) * CHANS;
    ((float4*)po)[0] = make_float4(o[0], o[1], o[2],  o[3]);
    ((float4*)po)[1] = make_float4(o[4], o[5], o[6],  o[7]);
    ((float4*)po)[2] = make_float4(o[8], o[9], o[10], o[11]);
}

extern "C" void kernel_launch(void* const* d_in, const int* in_sizes, int n_in,
                              void* d_out, int out_size, void* d_ws, size_t ws_size,
                              hipStream_t stream) {
    const float* U     = (const float*)d_in[0];
    const float* theta = (const float*)d_in[1];
    float* out = (float*)d_out;

    int blocks = BATCH * (OUT_H / 32) * (OUT_W / 32);   // 16384
    st_bilinear_kernel<<<blocks, 256, 0, stream>>>(U, theta, out);
}